// Round 1
// baseline (3175.737 us; speedup 1.0000x reference)
//
#include <hip/hip_runtime.h>
#include <math.h>

#define LEAKY 0.01f
#define BN_EPS 1e-5f
#define NSP 2048      // N superpixels
#define CIN 128       // C
#define HW_ 65536

// ---------------------------------------------------------------------------
// zero fill
__global__ void zero_fill(float* p, int n) {
    int i = blockIdx.x * 256 + threadIdx.x;
    if (i < n) p[i] = 0.0f;
}

// ---------------------------------------------------------------------------
// Phase 1: Hraw = Q^T @ x  (accumulated via atomics over K-splits), qsum = colsum(Q)
// grid(32 ntiles, 16 ksplit, 2 branch), block 256
__global__ __launch_bounds__(256) void qtx_kernel(
    const float* __restrict__ Q1, const float* __restrict__ x1,
    const float* __restrict__ Q2, const float* __restrict__ x2,
    float* __restrict__ Hraw1, float* __restrict__ qsum1,
    float* __restrict__ Hraw2, float* __restrict__ qsum2)
{
    const float* Q = blockIdx.z ? Q2 : Q1;
    const float* x = blockIdx.z ? x2 : x1;
    float* Hraw = blockIdx.z ? Hraw2 : Hraw1;
    float* qsum = blockIdx.z ? qsum2 : qsum1;

    int tid = threadIdx.x;
    int n0 = blockIdx.x * 64;
    int p0 = blockIdx.y * 4096;

    __shared__ float Qs[16][64];
    __shared__ float xs[16][128];

    float acc[4][8];
#pragma unroll
    for (int i = 0; i < 4; ++i)
#pragma unroll
        for (int j = 0; j < 8; ++j) acc[i][j] = 0.0f;
    float qacc = 0.0f;

    int nl = (tid % 16) * 4;
    int cl = (tid / 16) * 8;

    for (int pc = 0; pc < 4096; pc += 16) {
        // stage Q tile [16 p][64 n]
#pragma unroll
        for (int i = 0; i < 4; ++i) {
            int pk = i * 4 + tid / 64;
            Qs[pk][tid % 64] = Q[(size_t)(p0 + pc + pk) * NSP + n0 + (tid % 64)];
        }
        // stage x tile [16 p][128 c] (linear)
#pragma unroll
        for (int i = 0; i < 8; ++i) {
            int idx = i * 256 + tid;
            xs[idx / 128][idx % 128] = x[(size_t)(p0 + pc) * CIN + idx];
        }
        __syncthreads();

        if (tid < 64) {
#pragma unroll
            for (int pk = 0; pk < 16; ++pk) qacc += Qs[pk][tid];
        }

#pragma unroll
        for (int pk = 0; pk < 16; ++pk) {
            float4 q4 = *(const float4*)&Qs[pk][nl];
            float4 xa = *(const float4*)&xs[pk][cl];
            float4 xb = *(const float4*)&xs[pk][cl + 4];
            float qv[4] = {q4.x, q4.y, q4.z, q4.w};
            float xv[8] = {xa.x, xa.y, xa.z, xa.w, xb.x, xb.y, xb.z, xb.w};
#pragma unroll
            for (int i = 0; i < 4; ++i)
#pragma unroll
                for (int j = 0; j < 8; ++j) acc[i][j] = fmaf(qv[i], xv[j], acc[i][j]);
        }
        __syncthreads();
    }

#pragma unroll
    for (int i = 0; i < 4; ++i)
#pragma unroll
        for (int j = 0; j < 8; ++j)
            atomicAdd(&Hraw[(size_t)(n0 + nl + i) * CIN + cl + j], acc[i][j]);
    if (tid < 64) atomicAdd(&qsum[n0 + tid], qacc);
}

// ---------------------------------------------------------------------------
// H[r,c] /= qsum[r]   grid(2048, 2), block 128
__global__ void div_qsum(float* H1, const float* q1, float* H2, const float* q2) {
    float* H = blockIdx.y ? H2 : H1;
    const float* q = blockIdx.y ? q2 : q1;
    int r = blockIdx.x;
    H[(size_t)r * CIN + threadIdx.x] /= q[r];
}

// ---------------------------------------------------------------------------
// d[r] = 1/sqrt(rowsum(A) + 1)   grid(2048, 2), block 256
__global__ void arowsum(const float* __restrict__ A1, const float* __restrict__ A2,
                        float* d1, float* d2) {
    const float* A = blockIdx.y ? A2 : A1;
    float* d = blockIdx.y ? d2 : d1;
    int r = blockIdx.x, tid = threadIdx.x;
    float s = 0.0f;
    for (int j = tid; j < NSP; j += 256) s += A[(size_t)r * NSP + j];
    for (int o = 32; o > 0; o >>= 1) s += __shfl_down(s, o);
    __shared__ float ws_[4];
    if ((tid & 63) == 0) ws_[tid >> 6] = s;
    __syncthreads();
    if (tid == 0) d[r] = 1.0f / sqrtf(ws_[0] + ws_[1] + ws_[2] + ws_[3] + 1.0f);
}

// ---------------------------------------------------------------------------
// column stats, pass 1: partial sums over 64-row chunks. grid(F/64, 32), block 256
__global__ void colstats_partial(const float* __restrict__ X, int ld, int F,
                                 const float* __restrict__ g,
                                 float* __restrict__ Psum, float* __restrict__ Psq) {
    int tid = threadIdx.x;
    int f = blockIdx.x * 64 + (tid % 64);
    int rbase = blockIdx.y * 64;
    int rr = tid / 64;
    float s = 0.0f, q = 0.0f;
    if (g) {
        for (int i = 0; i < 16; ++i) {
            int r = rbase + rr * 16 + i;
            float v = X[(size_t)r * ld + f] * g[r];
            s += v; q = fmaf(v, v, q);
        }
    } else {
        for (int i = 0; i < 16; ++i) {
            int r = rbase + rr * 16 + i;
            float v = X[(size_t)r * ld + f];
            s += v; q = fmaf(v, v, q);
        }
    }
    __shared__ float Ls[4][64], Lq[4][64];
    Ls[rr][tid % 64] = s; Lq[rr][tid % 64] = q;
    __syncthreads();
    if (tid < 64) {
        float S = Ls[0][tid] + Ls[1][tid] + Ls[2][tid] + Ls[3][tid];
        float Qq = Lq[0][tid] + Lq[1][tid] + Lq[2][tid] + Lq[3][tid];
        Psum[(size_t)blockIdx.y * F + blockIdx.x * 64 + tid] = S;
        Psq[(size_t)blockIdx.y * F + blockIdx.x * 64 + tid] = Qq;
    }
}

// pass 2: mu, rstd.  grid(ceil(F/256)), block 256
__global__ void colstats_final(const float* __restrict__ Psum, const float* __restrict__ Psq,
                               int F, float eps, float* mu, float* rstd) {
    int f = blockIdx.x * 256 + threadIdx.x;
    if (f >= F) return;
    float s = 0.0f, q = 0.0f;
    for (int j = 0; j < 32; ++j) { s += Psum[(size_t)j * F + f]; q += Psq[(size_t)j * F + f]; }
    float m = s * (1.0f / 2048.0f);
    float var = q * (1.0f / 2048.0f) - m * m;
    if (var < 0.0f) var = 0.0f;
    mu[f] = m;
    rstd[f] = 1.0f / sqrtf(var + eps);
}

// ---------------------------------------------------------------------------
// GEMM1: T[n,f] = d[n] * ( sum_c BN(H)[n,c] * W[c,f] + bias[f] )
// grid(ceil(F/64), 32), block 256
__global__ __launch_bounds__(256) void gemm1_bn(
    const float* __restrict__ H, int K, const float* __restrict__ W, int F,
    const float* __restrict__ bias, const float* __restrict__ mu,
    const float* __restrict__ rstd, const float* __restrict__ d,
    float* __restrict__ T)
{
    int tid = threadIdx.x;
    int n0 = blockIdx.y * 64;
    int f0 = blockIdx.x * 64;
    __shared__ float As[16][64];
    __shared__ float Bs[16][64];
    int tx4 = (tid % 16) * 4, ty4 = (tid / 16) * 4;
    int am = tid / 4, ak = (tid % 4) * 4;
    int bk = tid / 16, bf = (tid % 16) * 4;
    float acc[4][4];
#pragma unroll
    for (int i = 0; i < 4; ++i)
#pragma unroll
        for (int j = 0; j < 4; ++j) acc[i][j] = 0.0f;

    for (int k0 = 0; k0 < K; k0 += 16) {
        float4 h = *(const float4*)&H[(size_t)(n0 + am) * K + k0 + ak];
        float4 m4 = *(const float4*)&mu[k0 + ak];
        float4 s4 = *(const float4*)&rstd[k0 + ak];
        As[ak + 0][am] = (h.x - m4.x) * s4.x;
        As[ak + 1][am] = (h.y - m4.y) * s4.y;
        As[ak + 2][am] = (h.z - m4.z) * s4.z;
        As[ak + 3][am] = (h.w - m4.w) * s4.w;
        float4 b = make_float4(0.f, 0.f, 0.f, 0.f);
        if (f0 + bf < F) b = *(const float4*)&W[(size_t)(k0 + bk) * F + f0 + bf];
        *(float4*)&Bs[bk][bf] = b;
        __syncthreads();
#pragma unroll
        for (int k = 0; k < 16; ++k) {
            float4 a = *(const float4*)&As[k][ty4];
            float4 bb = *(const float4*)&Bs[k][tx4];
            float av[4] = {a.x, a.y, a.z, a.w};
            float bv[4] = {bb.x, bb.y, bb.z, bb.w};
#pragma unroll
            for (int i = 0; i < 4; ++i)
#pragma unroll
                for (int j = 0; j < 4; ++j) acc[i][j] = fmaf(av[i], bv[j], acc[i][j]);
        }
        __syncthreads();
    }
#pragma unroll
    for (int i = 0; i < 4; ++i) {
        int n = n0 + ty4 + i;
        float dn = d[n];
        int f = f0 + tx4;
        if (f < F) {
#pragma unroll
            for (int j = 0; j < 4; ++j)
                T[(size_t)n * F + f + j] = dn * (acc[i][j] + bias[f + j]);
        }
    }
}

// ---------------------------------------------------------------------------
// GEMM2: Hout[n,f] = leaky( d[n] * ( sum_j A[n,j]*T[j,f] + T[n,f] ) )
// grid(ceil(F/64), 32), block 256
__global__ __launch_bounds__(256) void gemm2_adj(
    const float* __restrict__ A, const float* __restrict__ T, int F,
    const float* __restrict__ d, float* __restrict__ Hout)
{
    int tid = threadIdx.x;
    int n0 = blockIdx.y * 64;
    int f0 = blockIdx.x * 64;
    __shared__ float As[16][64];
    __shared__ float Bs[16][64];
    int tx4 = (tid % 16) * 4, ty4 = (tid / 16) * 4;
    int am = tid / 4, ak = (tid % 4) * 4;
    int bk = tid / 16, bf = (tid % 16) * 4;
    float acc[4][4];
#pragma unroll
    for (int i = 0; i < 4; ++i)
#pragma unroll
        for (int j = 0; j < 4; ++j) acc[i][j] = 0.0f;

    for (int k0 = 0; k0 < NSP; k0 += 16) {
        float4 a = *(const float4*)&A[(size_t)(n0 + am) * NSP + k0 + ak];
        As[ak + 0][am] = a.x;
        As[ak + 1][am] = a.y;
        As[ak + 2][am] = a.z;
        As[ak + 3][am] = a.w;
        float4 b = make_float4(0.f, 0.f, 0.f, 0.f);
        if (f0 + bf < F) b = *(const float4*)&T[(size_t)(k0 + bk) * F + f0 + bf];
        *(float4*)&Bs[bk][bf] = b;
        __syncthreads();
#pragma unroll
        for (int k = 0; k < 16; ++k) {
            float4 av4 = *(const float4*)&As[k][ty4];
            float4 bb = *(const float4*)&Bs[k][tx4];
            float av[4] = {av4.x, av4.y, av4.z, av4.w};
            float bv[4] = {bb.x, bb.y, bb.z, bb.w};
#pragma unroll
            for (int i = 0; i < 4; ++i)
#pragma unroll
                for (int j = 0; j < 4; ++j) acc[i][j] = fmaf(av[i], bv[j], acc[i][j]);
        }
        __syncthreads();
    }
#pragma unroll
    for (int i = 0; i < 4; ++i) {
        int n = n0 + ty4 + i;
        float dn = d[n];
        int f = f0 + tx4;
        if (f < F) {
#pragma unroll
            for (int j = 0; j < 4; ++j) {
                float v = dn * (acc[i][j] + T[(size_t)n * F + f + j]);
                Hout[(size_t)n * F + f + j] = v > 0.0f ? v : LEAKY * v;
            }
        }
    }
}

// ---------------------------------------------------------------------------
// cross-gate g[n] = exp(10*(1 - dot/(|H1||H2|))) - 1.  grid(2048), block 256
__global__ void rowgate(const float* __restrict__ H1, const float* __restrict__ H2,
                        int F, float* __restrict__ g) {
    int n = blockIdx.x, tid = threadIdx.x;
    float s11 = 0.f, s22 = 0.f, s12 = 0.f;
    for (int f = tid; f < F; f += 256) {
        float a = H1[(size_t)n * F + f], b = H2[(size_t)n * F + f];
        s11 = fmaf(a, a, s11); s22 = fmaf(b, b, s22); s12 = fmaf(a, b, s12);
    }
    for (int o = 32; o > 0; o >>= 1) {
        s11 += __shfl_down(s11, o); s22 += __shfl_down(s22, o); s12 += __shfl_down(s12, o);
    }
    __shared__ float r[3][4];
    if ((tid & 63) == 0) { int w = tid >> 6; r[0][w] = s11; r[1][w] = s22; r[2][w] = s12; }
    __syncthreads();
    if (tid == 0) {
        s11 = r[0][0] + r[0][1] + r[0][2] + r[0][3];
        s22 = r[1][0] + r[1][1] + r[1][2] + r[1][3];
        s12 = r[2][0] + r[2][1] + r[2][2] + r[2][3];
        float mod = sqrtf(s11) * sqrtf(s22);
        float c = 1.0f - s12 / mod;
        g[n] = expf(10.0f * c) - 1.0f;
    }
}

// out[r, colOff+f] = (X[r,f]*g[r] - mu[f]) * rstd[f].  grid(F/256, 2048), block 256
__global__ void gate_apply(const float* __restrict__ X, int F, const float* __restrict__ g,
                           const float* __restrict__ mu, const float* __restrict__ rstd,
                           float* __restrict__ out, int ldOut, int colOff) {
    int r = blockIdx.y;
    int f = blockIdx.x * 256 + threadIdx.x;
    float v = (X[(size_t)r * F + f] * g[r] - mu[f]) * rstd[f];
    out[(size_t)r * ldOut + colOff + f] = v;
}

// ---------------------------------------------------------------------------
// Final: Y = softmax(Q1 @ Hf @ Wc + bc).  grid(512), block 256; 128 rows/block
__global__ __launch_bounds__(256) void final_fused(
    const float* __restrict__ Q1, const float* __restrict__ Hf,
    const float* __restrict__ Wc, const float* __restrict__ bc,
    float* __restrict__ Y)
{
    int tid = threadIdx.x;
    int p0 = blockIdx.x * 128;
    __shared__ float Qs[16][128];
    __shared__ float Hs[16][32];
    int tr = tid / 8, tc = tid % 8;
    float acc[4][4];
#pragma unroll
    for (int i = 0; i < 4; ++i)
#pragma unroll
        for (int j = 0; j < 4; ++j) acc[i][j] = 0.0f;

    for (int k0 = 0; k0 < NSP; k0 += 16) {
#pragma unroll
        for (int pass = 0; pass < 2; ++pass) {
            int r = tid / 4 + pass * 64;
            int kk = (tid % 4) * 4;
            float4 q = *(const float4*)&Q1[(size_t)(p0 + r) * NSP + k0 + kk];
            Qs[kk + 0][r] = q.x; Qs[kk + 1][r] = q.y; Qs[kk + 2][r] = q.z; Qs[kk + 3][r] = q.w;
        }
        {
            float2 h = *(const float2*)&Hf[(size_t)(k0 + tid / 16) * 32 + (tid % 16) * 2];
            Hs[tid / 16][(tid % 16) * 2] = h.x;
            Hs[tid / 16][(tid % 16) * 2 + 1] = h.y;
        }
        __syncthreads();
#pragma unroll
        for (int k = 0; k < 16; ++k) {
            float4 q = *(const float4*)&Qs[k][tr * 4];
            float4 h = *(const float4*)&Hs[k][tc * 4];
            float qv[4] = {q.x, q.y, q.z, q.w};
            float hv[4] = {h.x, h.y, h.z, h.w};
#pragma unroll
            for (int i = 0; i < 4; ++i)
#pragma unroll
                for (int j = 0; j < 4; ++j) acc[i][j] = fmaf(qv[i], hv[j], acc[i][j]);
        }
        __syncthreads();
    }
    // project to 2 classes and reduce across the 8 lanes sharing a row group
    float l0[4], l1[4];
#pragma unroll
    for (int i = 0; i < 4; ++i) {
        l0[i] = 0.f; l1[i] = 0.f;
#pragma unroll
        for (int j = 0; j < 4; ++j) {
            int c = tc * 4 + j;
            l0[i] = fmaf(acc[i][j], Wc[c * 2 + 0], l0[i]);
            l1[i] = fmaf(acc[i][j], Wc[c * 2 + 1], l1[i]);
        }
    }
#pragma unroll
    for (int o = 1; o < 8; o <<= 1) {
#pragma unroll
        for (int i = 0; i < 4; ++i) {
            l0[i] += __shfl_xor(l0[i], o);
            l1[i] += __shfl_xor(l1[i], o);
        }
    }
    if (tc == 0) {
#pragma unroll
        for (int i = 0; i < 4; ++i) {
            float a = l0[i] + bc[0], b = l1[i] + bc[1];
            float m = fmaxf(a, b);
            float ea = expf(a - m), eb = expf(b - m);
            float inv = 1.0f / (ea + eb);
            int p = p0 + tr * 4 + i;
            Y[(size_t)p * 2 + 0] = ea * inv;
            Y[(size_t)p * 2 + 1] = eb * inv;
        }
    }
}

// ---------------------------------------------------------------------------
extern "C" void kernel_launch(void* const* d_in, const int* in_sizes, int n_in,
                              void* d_out, int out_size, void* d_ws, size_t ws_size,
                              hipStream_t stream) {
    const float* x1   = (const float*)d_in[0];
    const float* x2   = (const float*)d_in[1];
    const float* Q1   = (const float*)d_in[2];
    const float* Q2   = (const float*)d_in[3];
    const float* A1   = (const float*)d_in[4];
    const float* A2   = (const float*)d_in[5];
    const float* W1_0 = (const float*)d_in[6];
    const float* b1_0 = (const float*)d_in[7];
    const float* W1_1 = (const float*)d_in[8];
    const float* b1_1 = (const float*)d_in[9];
    const float* W2_0 = (const float*)d_in[10];
    const float* b2_0 = (const float*)d_in[11];
    const float* W2_1 = (const float*)d_in[12];
    const float* b2_1 = (const float*)d_in[13];
    const float* W_out = (const float*)d_in[14];
    const float* b_out = (const float*)d_in[15];
    const float* W_cls = (const float*)d_in[16];
    const float* b_cls = (const float*)d_in[17];
    float* Y = (float*)d_out;

    float* ws = (float*)d_ws;
    float* H1   = ws;                       // 2048*1024
    float* H2   = ws + 2097152;
    float* T1   = ws + 4194304;
    float* T2   = ws + 6291456;
    float* HC   = ws + 8388608;             // 2048*2048
    float* TOUT = ws + 12582912;            // 2048*32
    float* HFIN = ws + 12648448;            // 2048*32
    float* PSUM = ws + 12713984;            // 32*2048
    float* PSQ  = ws + 12779520;            // 32*2048
    float* QS1  = ws + 12845056;            // 2048 (QS2 contiguous)
    float* QS2  = ws + 12847104;
    float* D1   = ws + 12849152;
    float* D2   = ws + 12851200;
    float* G    = ws + 12853248;
    float* MU   = ws + 12855296;
    float* RSTD = ws + 12857344;

    // zero accumulators (ws is poisoned each call)
    zero_fill<<<1024, 256, 0, stream>>>(H1, NSP * CIN);
    zero_fill<<<1024, 256, 0, stream>>>(H2, NSP * CIN);
    zero_fill<<<16, 256, 0, stream>>>(QS1, 2 * NSP);

    // Phase 1: superpixel pooling
    qtx_kernel<<<dim3(32, 16, 2), 256, 0, stream>>>(Q1, x1, Q2, x2, H1, QS1, H2, QS2);
    div_qsum<<<dim3(2048, 2), 128, 0, stream>>>(H1, QS1, H2, QS2);
    arowsum<<<dim3(2048, 2), 256, 0, stream>>>(A1, A2, D1, D2);

    // ---- Layer 1 (128 -> 512) ----
    colstats_partial<<<dim3(2, 32), 256, 0, stream>>>(H1, 128, 128, nullptr, PSUM, PSQ);
    colstats_final<<<1, 256, 0, stream>>>(PSUM, PSQ, 128, BN_EPS, MU, RSTD);
    gemm1_bn<<<dim3(8, 32), 256, 0, stream>>>(H1, 128, W1_0, 512, b1_0, MU, RSTD, D1, T1);
    colstats_partial<<<dim3(2, 32), 256, 0, stream>>>(H2, 128, 128, nullptr, PSUM, PSQ);
    colstats_final<<<1, 256, 0, stream>>>(PSUM, PSQ, 128, BN_EPS, MU, RSTD);
    gemm1_bn<<<dim3(8, 32), 256, 0, stream>>>(H2, 128, W2_0, 512, b2_0, MU, RSTD, D2, T2);
    gemm2_adj<<<dim3(8, 32), 256, 0, stream>>>(A1, T1, 512, D1, H1);
    gemm2_adj<<<dim3(8, 32), 256, 0, stream>>>(A2, T2, 512, D2, H2);

    // ---- Cross-gate 1 (F=512), in-place ----
    rowgate<<<2048, 256, 0, stream>>>(H1, H2, 512, G);
    colstats_partial<<<dim3(8, 32), 256, 0, stream>>>(H1, 512, 512, G, PSUM, PSQ);
    colstats_final<<<2, 256, 0, stream>>>(PSUM, PSQ, 512, 0.0f, MU, RSTD);
    gate_apply<<<dim3(2, 2048), 256, 0, stream>>>(H1, 512, G, MU, RSTD, H1, 512, 0);
    colstats_partial<<<dim3(8, 32), 256, 0, stream>>>(H2, 512, 512, G, PSUM, PSQ);
    colstats_final<<<2, 256, 0, stream>>>(PSUM, PSQ, 512, 0.0f, MU, RSTD);
    gate_apply<<<dim3(2, 2048), 256, 0, stream>>>(H2, 512, G, MU, RSTD, H2, 512, 0);

    // ---- Layer 2 (512 -> 1024) ----
    colstats_partial<<<dim3(8, 32), 256, 0, stream>>>(H1, 512, 512, nullptr, PSUM, PSQ);
    colstats_final<<<2, 256, 0, stream>>>(PSUM, PSQ, 512, BN_EPS, MU, RSTD);
    gemm1_bn<<<dim3(16, 32), 256, 0, stream>>>(H1, 512, W1_1, 1024, b1_1, MU, RSTD, D1, T1);
    colstats_partial<<<dim3(8, 32), 256, 0, stream>>>(H2, 512, 512, nullptr, PSUM, PSQ);
    colstats_final<<<2, 256, 0, stream>>>(PSUM, PSQ, 512, BN_EPS, MU, RSTD);
    gemm1_bn<<<dim3(16, 32), 256, 0, stream>>>(H2, 512, W2_1, 1024, b2_1, MU, RSTD, D2, T2);
    gemm2_adj<<<dim3(16, 32), 256, 0, stream>>>(A1, T1, 1024, D1, H1);
    gemm2_adj<<<dim3(16, 32), 256, 0, stream>>>(A2, T2, 1024, D2, H2);

    // ---- Cross-gate 2 (F=1024) -> concat into HC [2048, 2048] ----
    rowgate<<<2048, 256, 0, stream>>>(H1, H2, 1024, G);
    colstats_partial<<<dim3(16, 32), 256, 0, stream>>>(H1, 1024, 1024, G, PSUM, PSQ);
    colstats_final<<<4, 256, 0, stream>>>(PSUM, PSQ, 1024, 0.0f, MU, RSTD);
    gate_apply<<<dim3(4, 2048), 256, 0, stream>>>(H1, 1024, G, MU, RSTD, HC, 2048, 0);
    colstats_partial<<<dim3(16, 32), 256, 0, stream>>>(H2, 1024, 1024, G, PSUM, PSQ);
    colstats_final<<<4, 256, 0, stream>>>(PSUM, PSQ, 1024, 0.0f, MU, RSTD);
    gate_apply<<<dim3(4, 2048), 256, 0, stream>>>(H2, 1024, G, MU, RSTD, HC, 2048, 1024);

    // ---- Output layer (2048 -> 32), uses A1h ----
    colstats_partial<<<dim3(32, 32), 256, 0, stream>>>(HC, 2048, 2048, nullptr, PSUM, PSQ);
    colstats_final<<<8, 256, 0, stream>>>(PSUM, PSQ, 2048, BN_EPS, MU, RSTD);
    gemm1_bn<<<dim3(1, 32), 256, 0, stream>>>(HC, 2048, W_out, 32, b_out, MU, RSTD, D1, TOUT);
    gemm2_adj<<<dim3(1, 32), 256, 0, stream>>>(A1, TOUT, 32, D1, HFIN);

    // ---- Final: softmax(Q1 @ HFIN @ W_cls + b_cls) ----
    final_fused<<<512, 256, 0, stream>>>(Q1, HFIN, W_cls, b_cls, Y);
}